// Round 1
// baseline (45.303 us; speedup 1.0000x reference)
//
#include <hip/hip_runtime.h>

#define Nn 4096
#define Dd 128

typedef __attribute__((ext_vector_type(8))) short  short8v;
typedef __attribute__((ext_vector_type(4))) float  float4v;

// log2(e) / mu, mu = 2.0
#define C_LOG2E_OVER_MU 0.7213475204444817f

__device__ __forceinline__ unsigned short f2bf(float f) {
  unsigned u = __float_as_uint(f);
  u += 0x7fffu + ((u >> 16) & 1u);   // round-to-nearest-even
  return (unsigned short)(u >> 16);
}

// ---------------- row norms: rows 0..4095 = X, 4096..8191 = Y ----------------
__global__ __launch_bounds__(256) void norms_kernel(const float* __restrict__ X,
                                                    const float* __restrict__ Y,
                                                    float* __restrict__ norms) {
  int wave = threadIdx.x >> 6;
  int lane = threadIdx.x & 63;
  int row = blockIdx.x * 4 + wave;            // 0..8191
  const float* src = (row < Nn) ? (X + (size_t)row * Dd)
                                : (Y + (size_t)(row - Nn) * Dd);
  float2 v = reinterpret_cast<const float2*>(src)[lane];
  float s = v.x * v.x + v.y * v.y;
#pragma unroll
  for (int off = 32; off > 0; off >>= 1) s += __shfl_xor(s, off);
  if (lane == 0) norms[row] = s;
}

// ---------------- fused pairwise-exp-sum: one 128x128 tile per block ----------
// q = blockIdx.z: 0 -> XX, 1 -> YY, 2 -> XY.  Diagonal excluded for q<2
// (added analytically in the final kernel).
__global__ __launch_bounds__(256) void mmd_main(const float* __restrict__ X,
                                                const float* __restrict__ Y,
                                                const float* __restrict__ norms,
                                                float* __restrict__ partials) {
  __shared__ __align__(16) char As[128 * 64 * 2];
  __shared__ __align__(16) char Bs[128 * 64 * 2];

  const int q = blockIdx.z;
  const float* Ab; const float* Bb; const float* nA; const float* nB;
  if (q == 0)      { Ab = X; Bb = X; nA = norms;      nB = norms;      }
  else if (q == 1) { Ab = Y; Bb = Y; nA = norms + Nn; nB = norms + Nn; }
  else             { Ab = X; Bb = Y; nA = norms;      nB = norms + Nn; }

  const int R0 = blockIdx.y * 128;
  const int C0 = blockIdx.x * 128;

  const int lane = threadIdx.x & 63;
  const int wave = threadIdx.x >> 6;
  const int wr = (wave >> 1) & 1;   // wave row (0..1), each owns 64 rows
  const int wc = wave & 1;          // wave col (0..1), each owns 64 cols
  const int lr = lane & 15;
  const int kq = lane >> 4;         // 0..3

  float4v acc[4][4];
#pragma unroll
  for (int m = 0; m < 4; ++m)
#pragma unroll
    for (int n = 0; n < 4; ++n)
      acc[m][n] = (float4v){0.f, 0.f, 0.f, 0.f};

  for (int chunk = 0; chunk < 2; ++chunk) {
    const int K0 = chunk * 64;
    // stage A and B tiles: 128 rows x 64 k each, fp32 -> bf16, XOR-swizzled
#pragma unroll
    for (int i = 0; i < 8; ++i) {
      int c = threadIdx.x + 256 * i;      // 0..2047 float4-chunks
      int row = c >> 4;                   // 0..127
      int col4 = (c & 15) << 2;           // 0..60
      float4v va = *reinterpret_cast<const float4v*>(Ab + (size_t)(R0 + row) * Dd + K0 + col4);
      float4v vb = *reinterpret_cast<const float4v*>(Bb + (size_t)(C0 + row) * Dd + K0 + col4);
      ushort4 ha = make_ushort4(f2bf(va.x), f2bf(va.y), f2bf(va.z), f2bf(va.w));
      ushort4 hb = make_ushort4(f2bf(vb.x), f2bf(vb.y), f2bf(vb.z), f2bf(vb.w));
      int off = ((row << 7) + (col4 << 1)) ^ ((row & 7) << 4);
      *reinterpret_cast<ushort4*>(As + off) = ha;
      *reinterpret_cast<ushort4*>(Bs + off) = hb;
    }
    __syncthreads();

#pragma unroll
    for (int kk = 0; kk < 2; ++kk) {
      const int kbyte = kk * 64 + kq * 16;
      short8v a[4], b[4];
#pragma unroll
      for (int m = 0; m < 4; ++m) {
        int row = wr * 64 + m * 16 + lr;
        int off = ((row << 7) + kbyte) ^ ((row & 7) << 4);
        a[m] = *reinterpret_cast<const short8v*>(As + off);
      }
#pragma unroll
      for (int n = 0; n < 4; ++n) {
        int row = wc * 64 + n * 16 + lr;
        int off = ((row << 7) + kbyte) ^ ((row & 7) << 4);
        b[n] = *reinterpret_cast<const short8v*>(Bs + off);
      }
#pragma unroll
      for (int m = 0; m < 4; ++m)
#pragma unroll
        for (int n = 0; n < 4; ++n)
          acc[m][n] = __builtin_amdgcn_mfma_f32_16x16x32_bf16(a[m], b[n], acc[m][n], 0, 0, 0);
    }
    __syncthreads();
  }

  // epilogue: exp2((2*dot - x2 - y2) * log2e/mu), diagonal masked for q<2
  float y2c[4];
#pragma unroll
  for (int n = 0; n < 4; ++n) y2c[n] = nB[C0 + wc * 64 + n * 16 + lr];

  float local = 0.f;
#pragma unroll
  for (int m = 0; m < 4; ++m) {
#pragma unroll
    for (int j = 0; j < 4; ++j) {
      int r = R0 + wr * 64 + m * 16 + kq * 4 + j;   // C/D: row=(lane>>4)*4+j
      float x2r = nA[r];
#pragma unroll
      for (int n = 0; n < 4; ++n) {
        int c = C0 + wc * 64 + n * 16 + lr;          // C/D: col=lane&15
        float s = acc[m][n][j];
        float arg = (2.f * s - x2r - y2c[n]) * C_LOG2E_OVER_MU;
        float e = __builtin_amdgcn_exp2f(arg);
        if (q == 2 || r != c) local += e;
      }
    }
  }

#pragma unroll
  for (int off = 32; off > 0; off >>= 1) local += __shfl_xor(local, off);

  float* red = reinterpret_cast<float*>(As);
  __syncthreads();
  if (lane == 0) red[wave] = local;
  __syncthreads();
  if (threadIdx.x == 0)
    partials[q * 1024 + blockIdx.y * 32 + blockIdx.x] = red[0] + red[1] + red[2] + red[3];
}

// ---------------- deterministic final reduction ------------------------------
__global__ __launch_bounds__(256) void mmd_final(const float* __restrict__ partials,
                                                 float* __restrict__ out) {
  const float a1 = 1.0f / 16773120.0f;   // 1/(4096^2-4096) = alpha1 = alpha2
  const float b2 = 2.0f / 16777216.0f;   // 2*beta (kxy sum == kyx sum)
  float v = 0.f;
  for (int i = threadIdx.x; i < 1024; i += 256)
    v += a1 * (partials[i] + partials[1024 + i]) - b2 * partials[2048 + i];
#pragma unroll
  for (int off = 32; off > 0; off >>= 1) v += __shfl_xor(v, off);
  __shared__ float red[4];
  if ((threadIdx.x & 63) == 0) red[threadIdx.x >> 6] = v;
  __syncthreads();
  if (threadIdx.x == 0) {
    float t = red[0] + red[1] + red[2] + red[3];
    // analytic diagonal: n*(alpha1+alpha2) = 2*4096/16773120 = 2/4095
    out[0] = t + (float)(2.0 / 4095.0);
  }
}

extern "C" void kernel_launch(void* const* d_in, const int* in_sizes, int n_in,
                              void* d_out, int out_size, void* d_ws, size_t ws_size,
                              hipStream_t stream) {
  const float* X = (const float*)d_in[0];
  const float* Y = (const float*)d_in[1];
  float* norms    = (float*)d_ws;        // 8192 floats
  float* partials = norms + 8192;        // 3072 floats
  float* out      = (float*)d_out;

  hipLaunchKernelGGL(norms_kernel, dim3(2048), dim3(256), 0, stream, X, Y, norms);
  hipLaunchKernelGGL(mmd_main, dim3(32, 32, 3), dim3(256), 0, stream, X, Y, norms, partials);
  hipLaunchKernelGGL(mmd_final, dim3(1), dim3(256), 0, stream, partials, out);
}

// Round 2
// 35.903 us; speedup vs baseline: 1.2618x; 1.2618x over previous
//
#include <hip/hip_runtime.h>

#define Nn 4096
#define Dd 128

typedef __attribute__((ext_vector_type(8))) short  short8v;

// log2(e)/mu, mu = 2.0
#define C_K   0.7213475204444817f
// 2*log2(e)/mu
#define C_2K  1.4426950408889634f
#define SKIP_CUTOFF -110.0f

__device__ __forceinline__ unsigned short f2bf(float f) {
  unsigned u = __float_as_uint(f);
  u += 0x7fffu + ((u >> 16) & 1u);   // round-to-nearest-even
  return (unsigned short)(u >> 16);
}

__device__ __forceinline__ void gload_lds16(const void* g, void* l) {
  __builtin_amdgcn_global_load_lds(
      (const __attribute__((address_space(1))) unsigned int*)g,
      (__attribute__((address_space(3))) unsigned int*)l, 16, 0, 0);
}

// ---- prep: row norms (fp32) + fp32->bf16 conversion, one pass --------------
// rows 0..4095 = X, 4096..8191 = Y
__global__ __launch_bounds__(256) void prep_kernel(const float* __restrict__ X,
                                                   const float* __restrict__ Y,
                                                   float* __restrict__ norms,
                                                   unsigned short* __restrict__ Xb,
                                                   unsigned short* __restrict__ Yb) {
  int wave = threadIdx.x >> 6;
  int lane = threadIdx.x & 63;
  int row = blockIdx.x * 4 + wave;            // 0..8191
  const float* src;
  unsigned short* dst;
  if (row < Nn) { src = X + (size_t)row * Dd;        dst = Xb + (size_t)row * Dd; }
  else          { src = Y + (size_t)(row - Nn) * Dd; dst = Yb + (size_t)(row - Nn) * Dd; }
  float2 v = reinterpret_cast<const float2*>(src)[lane];
  float s = v.x * v.x + v.y * v.y;
#pragma unroll
  for (int off = 32; off > 0; off >>= 1) s += __shfl_xor(s, off);
  ushort2 h;
  h.x = f2bf(v.x);
  h.y = f2bf(v.y);
  reinterpret_cast<ushort2*>(dst)[lane] = h;
  if (lane == 0) norms[row] = s;
}

// ---- fused pairwise-exp-sum: one 128x128 tile per block ---------------------
// q=0: XX (upper-tri blocks only, off-diag weight 2), q=1: YY (same), q=2: XY.
// LDS tiles are [128 rows][128 k] bf16, XOR-swizzled: data (row, kbyte) lives
// at byte row*256 + (kbyte ^ ((row&7)<<4)). global_load_lds writes LDS
// linearly (base + lane*16), so the swizzle is applied to the per-lane GLOBAL
// source address (inverse == same involution).
__global__ __launch_bounds__(256) void mmd_main(const unsigned short* __restrict__ Xb,
                                                const unsigned short* __restrict__ Yb,
                                                const float* __restrict__ norms,
                                                float* __restrict__ partials) {
  const int q  = blockIdx.z;
  const int bx = blockIdx.x;
  const int by = blockIdx.y;

  if (q < 2 && by > bx) {                     // symmetric quadrant: skip lower
    if (threadIdx.x == 0) partials[q * 1024 + by * 32 + bx] = 0.f;
    return;
  }

  __shared__ __align__(16) char As[128 * 256];
  __shared__ __align__(16) char Bs[128 * 256];

  const unsigned short* Asrc = (q == 1) ? Yb : Xb;
  const unsigned short* Bsrc = (q == 0) ? Xb : Yb;
  const float* nA = (q == 1) ? norms + Nn : norms;
  const float* nB = (q == 0) ? norms : norms + Nn;

  const int R0 = by * 128;
  const int C0 = bx * 128;

  const int lane = threadIdx.x & 63;
  const int wv   = threadIdx.x >> 6;
  const int wr = (wv >> 1) & 1;      // wave row (0..1): 64 output rows
  const int wc = wv & 1;             // wave col (0..1): 64 output cols
  const int lr = lane & 15;
  const int kq = lane >> 4;          // 0..3

  // ---- stage both 32KB tiles via global_load_lds (16B/lane), swizzled source
  {
    const int sub   = lane >> 4;            // row-within-4
    const int kslot = (lane & 15) << 4;     // swizzled 16B slot within 256B row
#pragma unroll
    for (int i = 0; i < 8; ++i) {
      int row   = wv * 32 + i * 4 + sub;    // 0..127 (w*32 keeps row&7 clean)
      int kbyte = kslot ^ ((row & 7) << 4); // inverse swizzle on the source
      const char* gA = (const char*)Asrc + (((size_t)(R0 + row)) << 8) + kbyte;
      const char* gB = (const char*)Bsrc + (((size_t)(C0 + row)) << 8) + kbyte;
      gload_lds16(gA, As + wv * 8192 + i * 1024);
      gload_lds16(gB, Bs + wv * 8192 + i * 1024);
    }
  }
  __syncthreads();

  // ---- MFMA: 4 k-steps of 32, 16 fragments per wave --------------------------
  float4 accv[4][4];
  typedef __attribute__((ext_vector_type(4))) float f32x4;
  f32x4 acc[4][4];
#pragma unroll
  for (int m = 0; m < 4; ++m)
#pragma unroll
    for (int n = 0; n < 4; ++n)
      acc[m][n] = (f32x4){0.f, 0.f, 0.f, 0.f};

#pragma unroll
  for (int ks = 0; ks < 4; ++ks) {
    const int kbase = ks * 64 + kq * 16;
    short8v a[4], b[4];
#pragma unroll
    for (int m = 0; m < 4; ++m) {
      int row = wr * 64 + m * 16 + lr;
      int off = (row << 8) + (kbase ^ ((row & 7) << 4));
      a[m] = *reinterpret_cast<const short8v*>(As + off);
    }
#pragma unroll
    for (int n = 0; n < 4; ++n) {
      int row = wc * 64 + n * 16 + lr;
      int off = (row << 8) + (kbase ^ ((row & 7) << 4));
      b[n] = *reinterpret_cast<const short8v*>(Bs + off);
    }
#pragma unroll
    for (int m = 0; m < 4; ++m)
#pragma unroll
      for (int n = 0; n < 4; ++n)
        acc[m][n] = __builtin_amdgcn_mfma_f32_16x16x32_bf16(a[m], b[n], acc[m][n], 0, 0, 0);
  }

  // ---- epilogue: exp2(2K*dot - K*x2 - K*y2) with flush-to-zero skip ----------
  const bool diagblk = (q < 2) && (bx == by);
  float cy[4];
#pragma unroll
  for (int n = 0; n < 4; ++n)
    cy[n] = -C_K * nB[C0 + wc * 64 + n * 16 + lr];

  float local = 0.f;
#pragma unroll
  for (int m = 0; m < 4; ++m) {
    const int rbase = R0 + wr * 64 + m * 16 + kq * 4;
    float ax[4];
#pragma unroll
    for (int j = 0; j < 4; ++j) ax[j] = -C_K * nA[rbase + j];
#pragma unroll
    for (int n = 0; n < 4; ++n) {
      const int c = C0 + wc * 64 + n * 16 + lr;
      float a0 = fmaf(acc[m][n][0], C_2K, ax[0] + cy[n]);
      float a1 = fmaf(acc[m][n][1], C_2K, ax[1] + cy[n]);
      float a2 = fmaf(acc[m][n][2], C_2K, ax[2] + cy[n]);
      float a3 = fmaf(acc[m][n][3], C_2K, ax[3] + cy[n]);
      float mx = fmaxf(fmaxf(a0, a1), fmaxf(a2, a3));
      if (__any(mx > SKIP_CUTOFF)) {
        float e0 = __builtin_amdgcn_exp2f(a0);
        float e1 = __builtin_amdgcn_exp2f(a1);
        float e2 = __builtin_amdgcn_exp2f(a2);
        float e3 = __builtin_amdgcn_exp2f(a3);
        if (!diagblk || rbase + 0 != c) local += e0;
        if (!diagblk || rbase + 1 != c) local += e1;
        if (!diagblk || rbase + 2 != c) local += e2;
        if (!diagblk || rbase + 3 != c) local += e3;
      }
    }
  }

#pragma unroll
  for (int off = 32; off > 0; off >>= 1) local += __shfl_xor(local, off);

  float* red = reinterpret_cast<float*>(As);
  __syncthreads();
  if (lane == 0) red[wv] = local;
  __syncthreads();
  if (threadIdx.x == 0) {
    float w = (q < 2 && bx != by) ? 2.f : 1.f;   // symmetric off-diag blocks
    partials[q * 1024 + by * 32 + bx] = (red[0] + red[1] + red[2] + red[3]) * w;
  }
}

// ---- deterministic final reduction ------------------------------------------
__global__ __launch_bounds__(256) void mmd_final(const float* __restrict__ partials,
                                                 float* __restrict__ out) {
  const float a1 = 1.0f / 16773120.0f;   // 1/(4096^2-4096) = alpha1 = alpha2
  const float b2 = 2.0f / 16777216.0f;   // 2*beta (kxy sum == kyx sum)
  float v = 0.f;
  for (int i = threadIdx.x; i < 1024; i += 256)
    v += a1 * (partials[i] + partials[1024 + i]) - b2 * partials[2048 + i];
#pragma unroll
  for (int off = 32; off > 0; off >>= 1) v += __shfl_xor(v, off);
  __shared__ float red[4];
  if ((threadIdx.x & 63) == 0) red[threadIdx.x >> 6] = v;
  __syncthreads();
  if (threadIdx.x == 0) {
    float t = red[0] + red[1] + red[2] + red[3];
    // analytic diagonal: n*(alpha1+alpha2) = 2/4095
    out[0] = t + (float)(2.0 / 4095.0);
  }
}

extern "C" void kernel_launch(void* const* d_in, const int* in_sizes, int n_in,
                              void* d_out, int out_size, void* d_ws, size_t ws_size,
                              hipStream_t stream) {
  const float* X = (const float*)d_in[0];
  const float* Y = (const float*)d_in[1];
  float* norms           = (float*)d_ws;                 // 8192 floats
  float* partials        = norms + 8192;                 // 3072 floats
  unsigned short* Xb     = (unsigned short*)(partials + 3072); // 4096*128 bf16
  unsigned short* Yb     = Xb + (size_t)Nn * Dd;               // 4096*128 bf16
  float* out             = (float*)d_out;

  hipLaunchKernelGGL(prep_kernel, dim3(2048), dim3(256), 0, stream, X, Y, norms, Xb, Yb);
  hipLaunchKernelGGL(mmd_main, dim3(32, 32, 3), dim3(256), 0, stream, Xb, Yb, norms, partials);
  hipLaunchKernelGGL(mmd_final, dim3(1), dim3(256), 0, stream, partials, out);
}

// Round 3
// 28.616 us; speedup vs baseline: 1.5831x; 1.2546x over previous
//
#include <hip/hip_runtime.h>

#define Nn 4096
#define NTRI 528              // 32*33/2 upper-tri 128x128 tiles
#define NBLK 2080             // 2*528 + 1024

typedef __attribute__((ext_vector_type(8))) short  short8v;
typedef __attribute__((ext_vector_type(4))) float  f32x4;

#define C_K   0.7213475204444817f   // log2(e)/mu, mu=2
#define C_2K  1.4426950408889634f   // 2*log2(e)/mu

__device__ __forceinline__ unsigned short f2bf(float f) {
  unsigned u = __float_as_uint(f);
  u += 0x7fffu + ((u >> 16) & 1u);   // round-to-nearest-even
  return (unsigned short)(u >> 16);
}

__device__ __forceinline__ void gload_lds16(const void* g, void* l) {
  __builtin_amdgcn_global_load_lds(
      (const __attribute__((address_space(1))) unsigned int*)g,
      (__attribute__((address_space(3))) unsigned int*)l, 16, 0, 0);
}

// ---- prep: bf16 cast + prescaled norms kn[row] = -K * ||row||^2 -------------
// rows 0..4095 = X, 4096..8191 = Y
__global__ __launch_bounds__(256) void prep_kernel(const float* __restrict__ X,
                                                   const float* __restrict__ Y,
                                                   float* __restrict__ kn,
                                                   unsigned short* __restrict__ Xb,
                                                   unsigned short* __restrict__ Yb) {
  int wave = threadIdx.x >> 6;
  int lane = threadIdx.x & 63;
  int row = blockIdx.x * 4 + wave;            // 0..8191
  const float* src;
  unsigned short* dst;
  if (row < Nn) { src = X + (size_t)row * 128;        dst = Xb + (size_t)row * 128; }
  else          { src = Y + (size_t)(row - Nn) * 128; dst = Yb + (size_t)(row - Nn) * 128; }
  float2 v = reinterpret_cast<const float2*>(src)[lane];
  float s = v.x * v.x + v.y * v.y;
#pragma unroll
  for (int off = 32; off > 0; off >>= 1) s += __shfl_xor(s, off);
  ushort2 h;
  h.x = f2bf(v.x);
  h.y = f2bf(v.y);
  reinterpret_cast<ushort2*>(dst)[lane] = h;
  if (lane == 0) kn[row] = -C_K * s;
}

// ---- fused pairwise-exp-sum, compact grid ------------------------------------
// t < 528:        q=0 (XX), upper-tri tile (by<=bx), off-diag weight 2
// 528 <= t <1056: q=1 (YY), same
// t >= 1056:      q=2 (XY), full 32x32
// 128x128 tile, K chunked at 64 -> 2x16KB LDS (single-buffered), 4 blocks/CU.
// LDS layout [128 rows][128 B], swizzled: (row,kb) at byte row*128 + (kb ^ ((row&7)<<4)).
// global_load_lds writes linearly, so the swizzle is pre-applied to the global src.
__global__ __launch_bounds__(256, 4) void mmd_main(const unsigned short* __restrict__ Xb,
                                                   const unsigned short* __restrict__ Yb,
                                                   const float* __restrict__ kn,
                                                   float* __restrict__ partials) {
  __shared__ __align__(16) char As[128 * 128];
  __shared__ __align__(16) char Bs[128 * 128];
  __shared__ float red[4];

  const int t = blockIdx.x;
  int q, bx, by;
  if (t < 2 * NTRI) {
    q = (t >= NTRI) ? 1 : 0;
    const int u = t - q * NTRI;
    int r = (int)((sqrtf(8.f * (float)u + 1.f) - 1.f) * 0.5f);
    while ((r + 1) * (r + 2) / 2 <= u) ++r;
    while (r * (r + 1) / 2 > u) --r;
    bx = r; by = u - r * (r + 1) / 2;          // by <= bx
  } else {
    q = 2;
    const int u = t - 2 * NTRI;
    by = u >> 5; bx = u & 31;
  }

  const unsigned short* Asrc = (q == 1) ? Yb : Xb;
  const unsigned short* Bsrc = (q == 0) ? Xb : Yb;
  const float* knA = (q == 1) ? kn + Nn : kn;
  const float* knB = (q == 0) ? kn : kn + Nn;
  const int R0 = by << 7, C0 = bx << 7;

  const int lane = threadIdx.x & 63;
  const int wv   = threadIdx.x >> 6;
  const int wr = wv >> 1, wc = wv & 1;    // 2x2 wave grid, 64x64 per wave
  const int lr = lane & 15, kq = lane >> 4;

  f32x4 acc[4][4];
#pragma unroll
  for (int m = 0; m < 4; ++m)
#pragma unroll
    for (int n = 0; n < 4; ++n)
      acc[m][n] = (f32x4){0.f, 0.f, 0.f, 0.f};

  const int srow  = lane >> 3;            // 0..7
  const int sslot = (lane & 7) << 4;      // 16B slot in 128B chunk-row
  const int sswz  = sslot ^ (srow << 4);  // pre-swizzled source slot

#pragma unroll
  for (int ch = 0; ch < 2; ++ch) {
    if (ch) __syncthreads();              // all reads of prev chunk done
    // stage 16KB A + 16KB B (this K-half): 4+4 gload_lds per wave
#pragma unroll
    for (int i = 0; i < 4; ++i) {
      const int row = (wv << 5) + (i << 3) + srow;       // 0..127, row&7==srow
      const size_t kb = (size_t)(ch << 7) + sswz;
      gload_lds16((const char*)Asrc + (((size_t)(R0 + row)) << 8) + kb,
                  As + (wv << 12) + (i << 10));
      gload_lds16((const char*)Bsrc + (((size_t)(C0 + row)) << 8) + kb,
                  Bs + (wv << 12) + (i << 10));
    }
    __syncthreads();

#pragma unroll
    for (int ks = 0; ks < 2; ++ks) {
      const int kb = (ks << 6) + (kq << 4);
      short8v a[4], b[4];
#pragma unroll
      for (int m = 0; m < 4; ++m) {
        const int row = (wr << 6) + (m << 4) + lr;
        a[m] = *reinterpret_cast<const short8v*>(As + (row << 7) + (kb ^ ((row & 7) << 4)));
      }
#pragma unroll
      for (int n = 0; n < 4; ++n) {
        const int row = (wc << 6) + (n << 4) + lr;
        b[n] = *reinterpret_cast<const short8v*>(Bs + (row << 7) + (kb ^ ((row & 7) << 4)));
      }
#pragma unroll
      for (int m = 0; m < 4; ++m)
#pragma unroll
        for (int n = 0; n < 4; ++n)
          acc[m][n] = __builtin_amdgcn_mfma_f32_16x16x32_bf16(a[m], b[n], acc[m][n], 0, 0, 0);
    }
  }

  // ---- epilogue: sum exp2(fma(s, 2K, knA[r]+knB[c])) --------------------------
  const bool diagblk = (q < 2) && (bx == by);
  float cy[4];
#pragma unroll
  for (int n = 0; n < 4; ++n) cy[n] = knB[C0 + (wc << 6) + (n << 4) + lr];

  float l0 = 0.f, l1 = 0.f, l2 = 0.f, l3 = 0.f;
#pragma unroll
  for (int m = 0; m < 4; ++m) {
    const int rbase = (wr << 6) + (m << 4) + (kq << 2);          // local row base
    const f32x4 ax = *reinterpret_cast<const f32x4*>(knA + R0 + rbase);
#pragma unroll
    for (int n = 0; n < 4; ++n) {
      const float e0 = __builtin_amdgcn_exp2f(fmaf(acc[m][n][0], C_2K, ax[0] + cy[n]));
      const float e1 = __builtin_amdgcn_exp2f(fmaf(acc[m][n][1], C_2K, ax[1] + cy[n]));
      const float e2 = __builtin_amdgcn_exp2f(fmaf(acc[m][n][2], C_2K, ax[2] + cy[n]));
      const float e3 = __builtin_amdgcn_exp2f(fmaf(acc[m][n][3], C_2K, ax[3] + cy[n]));
      if (diagblk) {
        const int cc = (wc << 6) + (n << 4) + lr;
        if (rbase + 0 != cc) l0 += e0;
        if (rbase + 1 != cc) l1 += e1;
        if (rbase + 2 != cc) l2 += e2;
        if (rbase + 3 != cc) l3 += e3;
      } else {
        l0 += e0; l1 += e1; l2 += e2; l3 += e3;
      }
    }
  }
  float local = (l0 + l1) + (l2 + l3);

#pragma unroll
  for (int off = 32; off > 0; off >>= 1) local += __shfl_xor(local, off);

  if (lane == 0) red[wv] = local;
  __syncthreads();
  if (threadIdx.x == 0) {
    float s = (red[0] + red[1]) + (red[2] + red[3]);
    float w;
    if (q < 2) w = ((bx == by) ? 1.f : 2.f) * (1.0f / 16773120.0f);  // alpha
    else       w = -2.0f / 16777216.0f;                               // -2*beta
    partials[t] = s * w;
  }
}

// ---- deterministic final reduction ------------------------------------------
__global__ __launch_bounds__(256) void mmd_final(const float* __restrict__ partials,
                                                 float* __restrict__ out) {
  float v = 0.f;
  for (int i = threadIdx.x; i < NBLK; i += 256) v += partials[i];
#pragma unroll
  for (int off = 32; off > 0; off >>= 1) v += __shfl_xor(v, off);
  __shared__ float red[4];
  if ((threadIdx.x & 63) == 0) red[threadIdx.x >> 6] = v;
  __syncthreads();
  if (threadIdx.x == 0) {
    // analytic diagonal: n*(alpha1+alpha2) = 2/4095
    out[0] = ((red[0] + red[1]) + (red[2] + red[3])) + (float)(2.0 / 4095.0);
  }
}

extern "C" void kernel_launch(void* const* d_in, const int* in_sizes, int n_in,
                              void* d_out, int out_size, void* d_ws, size_t ws_size,
                              hipStream_t stream) {
  const float* X = (const float*)d_in[0];
  const float* Y = (const float*)d_in[1];
  float* kn       = (float*)d_ws;                       // 8192 floats (-K*norm^2)
  float* partials = kn + 8192;                          // 2080 floats
  unsigned short* Xb = (unsigned short*)(partials + 2080);  // 16B-aligned (41088 bytes in)
  unsigned short* Yb = Xb + (size_t)Nn * 128;
  float* out = (float*)d_out;

  hipLaunchKernelGGL(prep_kernel, dim3(2048), dim3(256), 0, stream, X, Y, kn, Xb, Yb);
  hipLaunchKernelGGL(mmd_main, dim3(NBLK), dim3(256), 0, stream, Xb, Yb, kn, partials);
  hipLaunchKernelGGL(mmd_final, dim3(1), dim3(256), 0, stream, partials, out);
}